// Round 6
// baseline (245.176 us; speedup 1.0000x reference)
//
#include <hip/hip_runtime.h>
#include <cstddef>
#include <cstdint>

typedef float f32x4 __attribute__((ext_vector_type(4)));
typedef __bf16 bf16x8 __attribute__((ext_vector_type(8)));

constexpr int NB = 16;   // batch
constexpr int NP = 512;  // pieces
constexpr int ND = 1024; // dim
constexpr int NW = 400;  // words
constexpr int NT = 32;   // triggers
constexpr int NE = 64;   // entities
constexpr int NH = 600;  // hidden
// W0pre: [nc=5][kb=32] images (128n x 64k bf16, XOR swizzle) - slices a,b.
// W0pair: [nc=2][it=64] images (320n x 32c bf16, rotation swizzle):
//   chunk c<2 -> W0c k = it*16 + c*8 + j ; c>=2 -> W0d k = it*16 + (c-2)*8 + j
//   elem at row r, slot ((r>>1) + c) & 3 (addr r*32 + slot*8); n = nc*320 + r,
//   zero-padded for n >= 600.
constexpr int IMGP = 128 * 64;   // W0pre image elems
constexpr int IMGQ = 320 * 32;   // W0pair image elems

__device__ inline bf16x8 pack8(float a0, float a1, float a2, float a3,
                               float a4, float a5, float a6, float a7) {
    bf16x8 v;
    v[0] = (__bf16)a0; v[1] = (__bf16)a1; v[2] = (__bf16)a2; v[3] = (__bf16)a3;
    v[4] = (__bf16)a4; v[5] = (__bf16)a5; v[6] = (__bf16)a6; v[7] = (__bf16)a7;
    return v;
}

__device__ inline void dma16(const void* g, void* l) {
    __builtin_amdgcn_global_load_lds(
        (const __attribute__((address_space(1))) uint32_t*)g,
        (__attribute__((address_space(3))) uint32_t*)l, 16, 0, 0);
}

// Combined waitcnt+barrier in ONE asm so nothing is scheduled between them.
#define LGKM_BARRIER() \
    asm volatile("s_waitcnt lgkmcnt(0)\n\ts_barrier" ::: "memory")

// ---------------------------------------------------------------------------
// Span mean, compile-time trip bounds, CHUNKED unroll (4 words per chunk) to
// bound in-flight float4 loads (~16) and VGPR use (R2 lesson: silent spills).
// Per-active-word arithmetic identical to the serial version.
template <int MAXW>
__device__ inline float4 span_mean_cols(const float* __restrict__ pbase,
                                        const int* __restrict__ wrow,
                                        int s, int e) {
    int nw = e - s;
    int ps[MAXW], pe[MAXW];
#pragma unroll
    for (int w = 0; w < MAXW; ++w) {
        bool act = w < nw;
        int ww = s + w;
        ps[w] = act ? wrow[2 * ww] : 0;
        pe[w] = act ? wrow[2 * ww + 1] : 0;
    }
    float4 acc = make_float4(0.f, 0.f, 0.f, 0.f);
#pragma unroll
    for (int cb = 0; cb < MAXW; cb += 4) {
#pragma unroll
        for (int w = cb; w < cb + 4; ++w) {
            float4 wa = make_float4(0.f, 0.f, 0.f, 0.f);
#pragma unroll
            for (int p = 0; p < 4; ++p) {
                if (ps[w] + p < pe[w]) {
                    float4 v =
                        *(const float4*)(pbase + (size_t)(ps[w] + p) * ND);
                    wa.x += v.x; wa.y += v.y; wa.z += v.z; wa.w += v.w;
                }
            }
            if (pe[w] > ps[w]) {
                float wi = 1.0f / (float)(pe[w] - ps[w]);
                acc.x += wa.x * wi; acc.y += wa.y * wi;
                acc.z += wa.z * wi; acc.w += wa.w * wi;
            }
        }
    }
    return acc;
}

// ---------------------------------------------------------------------------
// Kernel 1 (fused prep): span means + W0 image builders + out zeroing.
// LDS 16.9 KB (T[32][132]; W0pre built in 2 passes of 32 k-rows).
// grid = 2240:
//   id in [0,1536):       span means (trig then ent blocks)
//   id in [1536,2240):    build W0pre/W0pair + zero d_out
__global__ __launch_bounds__(256) void prep_kernel(
    const float* __restrict__ piece, const int* __restrict__ widx,
    const int* __restrict__ tidx, const int* __restrict__ eidx,
    const float* __restrict__ W0, __bf16* __restrict__ W0pre,
    __bf16* __restrict__ W0pair, float* __restrict__ trig,
    float* __restrict__ ent, float* __restrict__ out, int out_size) {
    __shared__ float T[32][132];   // 16.9 KB
    int id = blockIdx.x;
    int t = threadIdx.x;
    if (id < NB * (NT + NE)) {
        // ---- span means directly from pieces (mean of word means) ----
        const int* idx;
        float* outp;
        int b;
        bool is_trig = id < NB * NT;
        if (is_trig) {
            b = id / NT; idx = tidx + id * 2; outp = trig + (size_t)id * ND;
        } else {
            int id2 = id - NB * NT;
            b = id2 / NE; idx = eidx + id2 * 2; outp = ent + (size_t)id2 * ND;
        }
        int s = idx[0], e = idx[1];
        int col = t * 4;
        const int* wrow = widx + b * NW * 2;
        const float* pbase = piece + (size_t)b * NP * ND + col;
        float4 acc = is_trig ? span_mean_cols<8>(pbase, wrow, s, e)
                             : span_mean_cols<12>(pbase, wrow, s, e);
        float inv = 1.0f / (float)(e - s);
        acc.x *= inv; acc.y *= inv; acc.z *= inv; acc.w *= inv;
        *(float4*)(outp + col) = acc;
    } else {
        int bid = id - NB * (NT + NE);
        if (bid < 160) {
            // ---- W0pre image build, 2 passes of 32 k-rows ----
            int kb = bid & 31, nc = bid >> 5;
            __bf16* img = W0pre + ((size_t)nc * 32 + kb) * IMGP;
#pragma unroll
            for (int h = 0; h < 2; ++h) {
                {
                    int kl = t >> 3;           // 0..31 local k-row
                    int n0 = (t & 7) * 16;     // 16 cols per thread
                    int kg = kb * 64 + h * 32 + kl;
                    const float* src = W0 + (size_t)kg * NH + nc * 128 + n0;
#pragma unroll
                    for (int g = 0; g < 4; ++g) {
                        int n = nc * 128 + n0 + g * 4;
                        float4 v = (n < NH) ? *(const float4*)(src + g * 4)
                                            : make_float4(0.f, 0.f, 0.f, 0.f);
                        *(float4*)&T[kl][n0 + g * 4] = v;
                    }
                }
                __syncthreads();
#pragma unroll
                for (int s = 0; s < 2; ++s) {
                    int idx = s * 256 + t;     // 0..511
                    int row = idx >> 2, cl = idx & 3, c = h * 4 + cl;
                    bf16x8 v = pack8(T[cl * 8 + 0][row], T[cl * 8 + 1][row],
                                     T[cl * 8 + 2][row], T[cl * 8 + 3][row],
                                     T[cl * 8 + 4][row], T[cl * 8 + 5][row],
                                     T[cl * 8 + 6][row], T[cl * 8 + 7][row]);
                    *(bf16x8*)&img[row * 64 + ((c ^ (row & 7)) << 3)] = v;
                }
                __syncthreads();
            }
        } else if (bid < 672) {
            int e = bid - 160;
            int it = e & 63, nc = (e >> 6) & 1, zz = e >> 7;
            float (*Tp)[84] = reinterpret_cast<float(*)[84]>(&T[0][0]);
            {
                int kidx = t >> 3, part = t & 7;   // 10 n per thread
                int korig = (kidx < 16) ? (2048 + it * 16 + kidx)
                                        : (3072 + it * 16 + (kidx - 16));
                const float* src = W0 + (size_t)korig * NH;
#pragma unroll
                for (int g = 0; g < 10; ++g) {
                    int n = nc * 320 + zz * 80 + part * 10 + g;
                    Tp[kidx][part * 10 + g] = (n < NH) ? src[n] : 0.0f;
                }
            }
            __syncthreads();
            __bf16* img = W0pair + ((size_t)nc * 64 + it) * IMGQ;
#pragma unroll
            for (int s = 0; s < 2; ++s) {
                int idx = s * 256 + t;   // (rloc, c)
                if (idx < 320) {
                    int rloc = idx >> 2, c = idx & 3;
                    bf16x8 v = pack8(Tp[c * 8 + 0][rloc], Tp[c * 8 + 1][rloc],
                                     Tp[c * 8 + 2][rloc], Tp[c * 8 + 3][rloc],
                                     Tp[c * 8 + 4][rloc], Tp[c * 8 + 5][rloc],
                                     Tp[c * 8 + 6][rloc], Tp[c * 8 + 7][rloc]);
                    int rg = zz * 80 + rloc;
                    int slot = ((rg >> 1) + c) & 3;
                    *(bf16x8*)&img[rg * 32 + slot * 8] = v;
                }
            }
        } else {
            int j = ((bid - 672) * 256 + t) * 8;
            float4 z = make_float4(0.f, 0.f, 0.f, 0.f);
            if (j + 8 <= out_size) {
                *(float4*)(out + j) = z;
                *(float4*)(out + j + 4) = z;
            }
        }
    }
}

// ---------------------------------------------------------------------------
// Kernel 2: pre-projection GEMMs. Full-K single pass, plain direct stores,
// 3-buffer counted-vmcnt pipeline (R5 config, FROZEN).
// 64x64 tiles, block = 256 (4 waves, 2x2 of 32x32).
// grid = (24 mtile [0..7 trig, 8..23 ent], 10 ntile of 64).
__global__ __launch_bounds__(256) void pre_mfma_kernel(
    const float* __restrict__ trig, const float* __restrict__ ent,
    const __bf16* __restrict__ W0pre, float* __restrict__ pre_t,
    float* __restrict__ pre_e) {
    __shared__ __bf16 As[2][64 * 64];
    __shared__ __bf16 Bs[3][64 * 64];
    int mt8 = blockIdx.x, ntile = blockIdx.y;
    const float* A;
    float* C;
    int kbofs, mbase;
    if (mt8 < 8) { A = trig; C = pre_t; kbofs = 0;  mbase = mt8 * 64; }
    else         { A = ent;  C = pre_e; kbofs = 16; mbase = (mt8 - 8) * 64; }
    int tid = threadIdx.x;
    int lane = tid & 63, w = tid >> 6, rw = w & 1, cw = w >> 1;
    int q = lane >> 4, l15 = lane & 15, sa = l15 & 7;
    int nc = ntile >> 1, half = ntile & 1;
    const __bf16* imgbase =
        W0pre + ((size_t)nc * 32 + kbofs) * IMGP + half * 4096;
    int ar = tid >> 2, seg = tid & 3;
    f32x4 acc[2][2] = {};
    float4 av[4];

    auto dma_bb = [&](int it, int buf) {
        const __bf16* img = imgbase + (size_t)it * IMGP;
#pragma unroll
        for (int i = 0; i < 2; ++i) {
            int idx = i * 4 + w;
            dma16(img + idx * 512 + lane * 8, (__bf16*)Bs[buf] + idx * 512);
        }
    };
    auto load_a = [&](int it) {
        const float* src = A + (size_t)(mbase + ar) * ND + it * 64;
#pragma unroll
        for (int i = 0; i < 2; ++i) {
            int c = seg * 2 + i;
            av[i * 2]     = *(const float4*)(src + c * 8);
            av[i * 2 + 1] = *(const float4*)(src + c * 8 + 4);
        }
    };
    auto write_a = [&](int buf) {
#pragma unroll
        for (int i = 0; i < 2; ++i) {
            int c = seg * 2 + i;
            float4 a0 = av[i * 2], a1 = av[i * 2 + 1];
            *(bf16x8*)&As[buf][ar * 64 + ((c ^ (ar & 7)) << 3)] =
                pack8(a0.x, a0.y, a0.z, a0.w, a1.x, a1.y, a1.z, a1.w);
        }
    };
    auto mfma_t = [&](int abuf, int bbuf) {
#pragma unroll
        for (int ks = 0; ks < 2; ++ks) {
            int coff = ((q ^ sa) ^ (ks << 2)) << 3;
            bf16x8 af[2];
#pragma unroll
            for (int mt = 0; mt < 2; ++mt)
                af[mt] = *(const bf16x8*)&As[abuf][(32 * rw + 16 * mt + l15) * 64 + coff];
#pragma unroll
            for (int nt = 0; nt < 2; ++nt) {
                bf16x8 bf = *(const bf16x8*)&Bs[bbuf][(32 * cw + 16 * nt + l15) * 64 + coff];
#pragma unroll
                for (int mt = 0; mt < 2; ++mt)
                    acc[mt][nt] = __builtin_amdgcn_mfma_f32_16x16x32_bf16(
                        af[mt], bf, acc[mt][nt], 0, 0, 0);
            }
        }
    };

    // preamble: A(0) loads oldest, then DMA(0), DMA(1); full drain once.
    load_a(0);
    dma_bb(0, 0);
    dma_bb(1, 1);
    write_a(0);
    __syncthreads();

    int bc = 0, bp = 2;
    for (int it = 0; it < 16; ++it) {
        int acur = it & 1, anxt = acur ^ 1;
        if (it < 15) load_a(it + 1);       // oldest new loads
        if (it < 14) dma_bb(it + 2, bp);   // 2-ahead, stays in flight
        __builtin_amdgcn_s_setprio(1);
        mfma_t(acur, bc);
        __builtin_amdgcn_s_setprio(0);
        if (it < 15) write_a(anxt);        // vm-wait drains dma(it+1)
        LGKM_BARRIER();
        bc = (bc == 2) ? 0 : bc + 1;
        bp = (bp == 2) ? 0 : bp + 1;
    }

#pragma unroll
    for (int mt = 0; mt < 2; ++mt)
#pragma unroll
        for (int r = 0; r < 4; ++r) {
            float* crow =
                C + (size_t)(mbase + 32 * rw + 16 * mt + 4 * q + r) * NH;
#pragma unroll
            for (int nt = 0; nt < 2; ++nt) {
                int n = ntile * 64 + 32 * cw + 16 * nt + l15;
                if (n < NH) crow[n] = acc[mt][nt][r];
            }
        }
}

// ---------------------------------------------------------------------------
// Kernel 3: pairwise GEMM + fused FFN epilogue. M-SPLIT (this round):
// one trigger per block: grid (16 b, 32 tp, 2 nc), M=64 (e rows), N=320.
// Per-thread acc halves to 80 f32 -> regs/wave ~ 80 AGPR + ~88 arch <= 168,
// targeted by __launch_bounds__(256,3): 3 waves/SIMD = 12 waves/CU (was 7).
// t*e / |t-e| staging totals are UNCHANGED (each (t,e,k) computed once per
// nc); write_x per thread halves; Ts shrinks to 4 KB. LDS 52 KB -> exactly
// 3 blocks/CU (159.7 KB). Same rotation-swizzle machinery, same pipelined
// odd/even loop with 2-deep e-prefetch, write_x-before-mfma, setprio.
__global__ __launch_bounds__(256, 3) void pair_mfma_kernel(
    const float* __restrict__ trig, const float* __restrict__ ent,
    const __bf16* __restrict__ W0pair, const float* __restrict__ b0,
    const float* __restrict__ pre_t, const float* __restrict__ pre_e,
    const float* __restrict__ W1, const float* __restrict__ b1,
    float* __restrict__ out) {
    __shared__ __bf16 Xs[2][64 * 32];    // 2 x 4 KB
    __shared__ __bf16 Bs[2][320 * 32];   // 2 x 20 KB
    __shared__ float Ts[1024];           // 4 KB: one trigger row, f32
    int b = blockIdx.x, tp = blockIdx.y, nc = blockIdx.z;
    int tid = threadIdx.x;
    int lane = tid & 63, w = tid >> 6;
    int cw = w;                          // wave = N-quarter (80 cols)
    int q = lane >> 4, l15 = lane & 15;
    int xr = tid >> 2, xq = tid & 3;     // X staging: e-row 0..63, col-group
    const float* t0row = trig + (size_t)(b * NT + tp) * ND;
    const float* erow = ent + (size_t)(b * NE + xr) * ND;
    const __bf16* imgbase = W0pair + (size_t)nc * 64 * IMGQ;
    f32x4 acc[4][5] = {};
    float4 efA0, efA1, efB0, efB1;       // two named e-prefetch slots

    auto dma_b = [&](int it, int buf) {
        const __bf16* img = imgbase + (size_t)it * IMGQ + w * 2560;
        __bf16* lds = &Bs[buf][w * 2560];
#pragma unroll
        for (int i = 0; i < 5; ++i)
            dma16(img + i * 512 + lane * 8, lds + i * 512);
    };
    auto load_eA = [&](int it) {
        const float* er = erow + it * 16 + (xq & 1) * 8;
        efA0 = *(const float4*)er;
        efA1 = *(const float4*)(er + 4);
    };
    auto load_eB = [&](int it) {
        const float* er = erow + it * 16 + (xq & 1) * 8;
        efB0 = *(const float4*)er;
        efB1 = *(const float4*)(er + 4);
    };
    // Thread (xr, xq) produces col-group xq of X row xr: groups 0,1 = t*e
    // (k-halves 0,1), groups 2,3 = |t-e| (k-halves 0,1). Rotation slot
    // ((xr>>1)+xq)&3 matches the reader's ((r>>1)+q)&3.
    auto write_x = [&](int it, int buf, float4 e0, float4 e1) {
        const float* tsp = &Ts[it * 16 + (xq & 1) * 8];
        float4 t0 = *(const float4*)tsp;
        float4 t1 = *(const float4*)(tsp + 4);
        float tf[8], ef[8];
        tf[0] = t0.x; tf[1] = t0.y; tf[2] = t0.z; tf[3] = t0.w;
        tf[4] = t1.x; tf[5] = t1.y; tf[6] = t1.z; tf[7] = t1.w;
        ef[0] = e0.x; ef[1] = e0.y; ef[2] = e0.z; ef[3] = e0.w;
        ef[4] = e1.x; ef[5] = e1.y; ef[6] = e1.z; ef[7] = e1.w;
        bool prod = (xq < 2);
        float vj[8];
#pragma unroll
        for (int j = 0; j < 8; ++j) {
            float p = tf[j] * ef[j];
            float d = fabsf(tf[j] - ef[j]);
            vj[j] = prod ? p : d;
        }
        int slot = ((xr >> 1) + xq) & 3;
        *(bf16x8*)&Xs[buf][xr * 32 + slot * 8] =
            pack8(vj[0], vj[1], vj[2], vj[3], vj[4], vj[5], vj[6], vj[7]);
    };
    auto mfma_tile = [&](int buf) {
        const __bf16* X = Xs[buf];
        const __bf16* Bb = Bs[buf];
        bf16x8 af[4];
#pragma unroll
        for (int mt = 0; mt < 4; ++mt) {
            int r = 16 * mt + l15;
            af[mt] = *(const bf16x8*)&X[r * 32 + (((r >> 1) + q) & 3) * 8];
        }
        __builtin_amdgcn_s_setprio(1);
#pragma unroll
        for (int nt = 0; nt < 5; ++nt) {
            int r = 80 * cw + 16 * nt + l15;
            bf16x8 bv = *(const bf16x8*)&Bb[r * 32 + (((r >> 1) + q) & 3) * 8];
#pragma unroll
            for (int mt = 0; mt < 4; ++mt)
                acc[mt][nt] = __builtin_amdgcn_mfma_f32_16x16x32_bf16(
                    af[mt], bv, acc[mt][nt], 0, 0, 0);
        }
        __builtin_amdgcn_s_setprio(0);
    };

    // --- preamble: trigger row -> Ts (f32, straight copy: 1024 f32) ---
    *(float4*)&Ts[tid * 4] = *(const float4*)(t0row + tid * 4);
    load_eA(0);                  // write_x(0) consumes slot A
    dma_b(0, 0);
    __syncthreads();             // Ts + B(0) + e(0) ready (full drain)
    load_eB(1);                  // issue early; overlaps write_x(0) VALU
    write_x(0, 0, efA0, efA1);
    __syncthreads();             // X(0) visible

    // Main loop, 2 iters per body for static ef-slot + buffer indices.
    // write_x(it) consumes slot (it&1): A=even, B=odd.
    for (int itp = 0; itp < 32; ++itp) {
        int it0 = itp * 2;       // even: cur=0, nxt=1
        int it1 = it0 + 1;       // odd:  cur=1, nxt=0
        // --- even iteration ---
        if (it0 < 62) load_eA(it0 + 2);          // fills slot A (even)
        dma_b(it0 + 1, 1);
        write_x(it0 + 1, 1, efB0, efB1);         // slot B (odd), loaded 1 iter ago
        mfma_tile(0);
        __syncthreads();         // drains dma(it0+1) + e-loads, publishes X
        // --- odd iteration ---
        if (it1 < 62) load_eB(it1 + 2);          // fills slot B (odd)
        if (it1 < 63) {
            dma_b(it1 + 1, 0);
            write_x(it1 + 1, 0, efA0, efA1);     // slot A (even)
        }
        mfma_tile(1);
        __syncthreads();
    }

    // --- epilogue: h = relu(acc + pre_t + pre_e + b0); out += h @ W1 ---
    int tglob = b * NT + tp;
    const float* preT = pre_t + (size_t)tglob * NH;
    float w10[5], w11[5], b0v[5], ptv[5];
    int nbase = nc * 320 + 80 * cw + l15;
#pragma unroll
    for (int nt = 0; nt < 5; ++nt) {
        int n = nbase + 16 * nt;
        bool v = n < NH;
        w10[nt] = v ? W1[2 * n] : 0.f;
        w11[nt] = v ? W1[2 * n + 1] : 0.f;
        b0v[nt] = v ? b0[n] : 0.f;
        ptv[nt] = v ? preT[n] : 0.f;
    }
    float b10 = b1[0], b11 = b1[1];
    bool lead = (l15 == 0);
    bool addb = (nc == 0) && (cw == 0);
#pragma unroll
    for (int mt = 0; mt < 4; ++mt) {
#pragma unroll
        for (int r = 0; r < 4; ++r) {
            int e = 16 * mt + 4 * q + r;
            const float* preE = pre_e + (size_t)(b * NE + e) * NH;
            float s0 = 0.f, s1 = 0.f;
#pragma unroll
            for (int nt = 0; nt < 5; ++nt) {
                int n = nbase + 16 * nt;
                float pe = (n < NH) ? preE[n] : 0.f;
                float h = acc[mt][nt][r] + ptv[nt] + pe + b0v[nt];
                h = fmaxf(h, 0.f);
                s0 += h * w10[nt];
                s1 += h * w11[nt];
            }
#pragma unroll
            for (int m = 8; m >= 1; m >>= 1) {
                s0 += __shfl_xor(s0, m);
                s1 += __shfl_xor(s1, m);
            }
            if (lead) {
                if (addb) { s0 += b10; s1 += b11; }
                float* o = out + ((size_t)(tglob * NE + e)) * 2;
                atomicAdd(o, s0);
                atomicAdd(o + 1, s1);
            }
        }
    }
}

// ---------------------------------------------------------------------------
extern "C" void kernel_launch(void* const* d_in, const int* in_sizes, int n_in,
                              void* d_out, int out_size, void* d_ws,
                              size_t ws_size, hipStream_t stream) {
    const float* piece = (const float*)d_in[0];
    const int* widx = (const int*)d_in[1];
    const int* tidx = (const int*)d_in[2];
    const int* eidx = (const int*)d_in[3];
    const float* W0 = (const float*)d_in[4];
    const float* b0 = (const float*)d_in[5];
    const float* W1 = (const float*)d_in[6];
    const float* b1 = (const float*)d_in[7];
    float* out = (float*)d_out;

    float* ws = (float*)d_ws;
    float* trig = ws;                               // NB*NT*ND f32
    float* ent = trig + (size_t)NB * NT * ND;       // NB*NE*ND f32
    float* pre_t = ent + (size_t)NB * NE * ND;      // NB*NT*NH f32
    float* pre_e = pre_t + (size_t)NB * NT * NH;    // NB*NE*NH f32
    __bf16* W0pre = (__bf16*)(pre_e + (size_t)NB * NE * NH); // 5*32*IMGP bf16
    __bf16* W0pair = W0pre + (size_t)5 * 32 * IMGP;          // 2*64*IMGQ bf16

    // 3 launches: prep (span + builders + zeroing), pre (full-K), pair.
    int nprep = NB * (NT + NE) + 704;  // 1536 + 704
    prep_kernel<<<nprep, 256, 0, stream>>>(piece, widx, tidx, eidx, W0, W0pre,
                                           W0pair, trig, ent, out, out_size);
    pre_mfma_kernel<<<dim3(24, 10), 256, 0, stream>>>(trig, ent, W0pre,
                                                      pre_t, pre_e);
    pair_mfma_kernel<<<dim3(16, 32, 2), 256, 0, stream>>>(
        trig, ent, W0pair, b0, pre_t, pre_e, W1, b1, out);
}

// Round 7
// 203.439 us; speedup vs baseline: 1.2052x; 1.2052x over previous
//
#include <hip/hip_runtime.h>
#include <cstddef>
#include <cstdint>

typedef float f32x4 __attribute__((ext_vector_type(4)));
typedef __bf16 bf16x8 __attribute__((ext_vector_type(8)));

constexpr int NB = 16;   // batch
constexpr int NP = 512;  // pieces
constexpr int ND = 1024; // dim
constexpr int NW = 400;  // words
constexpr int NT = 32;   // triggers
constexpr int NE = 64;   // entities
constexpr int NH = 600;  // hidden
// W0pre: [nc=5][kb=32] images (128n x 64k bf16, XOR swizzle) - slices a,b.
// W0pair: [nc=2][it=64] images (320n x 32c bf16, rotation swizzle):
//   chunk c<2 -> W0c k = it*16 + c*8 + j ; c>=2 -> W0d k = it*16 + (c-2)*8 + j
//   elem at row r, slot ((r>>1) + c) & 3 (addr r*32 + slot*8); n = nc*320 + r,
//   zero-padded for n >= 600.
constexpr int IMGP = 128 * 64;   // W0pre image elems
constexpr int IMGQ = 320 * 32;   // W0pair image elems

__device__ inline bf16x8 pack8(float a0, float a1, float a2, float a3,
                               float a4, float a5, float a6, float a7) {
    bf16x8 v;
    v[0] = (__bf16)a0; v[1] = (__bf16)a1; v[2] = (__bf16)a2; v[3] = (__bf16)a3;
    v[4] = (__bf16)a4; v[5] = (__bf16)a5; v[6] = (__bf16)a6; v[7] = (__bf16)a7;
    return v;
}

__device__ inline void dma16(const void* g, void* l) {
    __builtin_amdgcn_global_load_lds(
        (const __attribute__((address_space(1))) uint32_t*)g,
        (__attribute__((address_space(3))) uint32_t*)l, 16, 0, 0);
}

// Combined waitcnt+barrier in ONE asm so nothing is scheduled between them.
#define LGKM_BARRIER() \
    asm volatile("s_waitcnt lgkmcnt(0)\n\ts_barrier" ::: "memory")

// ---------------------------------------------------------------------------
// Span mean, compile-time trip bounds, CHUNKED unroll (4 words per chunk) to
// bound in-flight float4 loads (~16) and VGPR use (R2 lesson: silent spills).
// Per-active-word arithmetic identical to the serial version.
template <int MAXW>
__device__ inline float4 span_mean_cols(const float* __restrict__ pbase,
                                        const int* __restrict__ wrow,
                                        int s, int e) {
    int nw = e - s;
    int ps[MAXW], pe[MAXW];
#pragma unroll
    for (int w = 0; w < MAXW; ++w) {
        bool act = w < nw;
        int ww = s + w;
        ps[w] = act ? wrow[2 * ww] : 0;
        pe[w] = act ? wrow[2 * ww + 1] : 0;
    }
    float4 acc = make_float4(0.f, 0.f, 0.f, 0.f);
#pragma unroll
    for (int cb = 0; cb < MAXW; cb += 4) {
#pragma unroll
        for (int w = cb; w < cb + 4; ++w) {
            float4 wa = make_float4(0.f, 0.f, 0.f, 0.f);
#pragma unroll
            for (int p = 0; p < 4; ++p) {
                if (ps[w] + p < pe[w]) {
                    float4 v =
                        *(const float4*)(pbase + (size_t)(ps[w] + p) * ND);
                    wa.x += v.x; wa.y += v.y; wa.z += v.z; wa.w += v.w;
                }
            }
            if (pe[w] > ps[w]) {
                float wi = 1.0f / (float)(pe[w] - ps[w]);
                acc.x += wa.x * wi; acc.y += wa.y * wi;
                acc.z += wa.z * wi; acc.w += wa.w * wi;
            }
        }
    }
    return acc;
}

// ---------------------------------------------------------------------------
// Kernel 1 (fused prep): span means + W0 image builders + out zeroing.
// LDS 16.9 KB (T[32][132]; W0pre built in 2 passes of 32 k-rows).
// grid = 2240:
//   id in [0,1536):       span means (trig then ent blocks)
//   id in [1536,2240):    build W0pre/W0pair + zero d_out
__global__ __launch_bounds__(256) void prep_kernel(
    const float* __restrict__ piece, const int* __restrict__ widx,
    const int* __restrict__ tidx, const int* __restrict__ eidx,
    const float* __restrict__ W0, __bf16* __restrict__ W0pre,
    __bf16* __restrict__ W0pair, float* __restrict__ trig,
    float* __restrict__ ent, float* __restrict__ out, int out_size) {
    __shared__ float T[32][132];   // 16.9 KB
    int id = blockIdx.x;
    int t = threadIdx.x;
    if (id < NB * (NT + NE)) {
        // ---- span means directly from pieces (mean of word means) ----
        const int* idx;
        float* outp;
        int b;
        bool is_trig = id < NB * NT;
        if (is_trig) {
            b = id / NT; idx = tidx + id * 2; outp = trig + (size_t)id * ND;
        } else {
            int id2 = id - NB * NT;
            b = id2 / NE; idx = eidx + id2 * 2; outp = ent + (size_t)id2 * ND;
        }
        int s = idx[0], e = idx[1];
        int col = t * 4;
        const int* wrow = widx + b * NW * 2;
        const float* pbase = piece + (size_t)b * NP * ND + col;
        float4 acc = is_trig ? span_mean_cols<8>(pbase, wrow, s, e)
                             : span_mean_cols<12>(pbase, wrow, s, e);
        float inv = 1.0f / (float)(e - s);
        acc.x *= inv; acc.y *= inv; acc.z *= inv; acc.w *= inv;
        *(float4*)(outp + col) = acc;
    } else {
        int bid = id - NB * (NT + NE);
        if (bid < 160) {
            // ---- W0pre image build, 2 passes of 32 k-rows ----
            int kb = bid & 31, nc = bid >> 5;
            __bf16* img = W0pre + ((size_t)nc * 32 + kb) * IMGP;
#pragma unroll
            for (int h = 0; h < 2; ++h) {
                {
                    int kl = t >> 3;           // 0..31 local k-row
                    int n0 = (t & 7) * 16;     // 16 cols per thread
                    int kg = kb * 64 + h * 32 + kl;
                    const float* src = W0 + (size_t)kg * NH + nc * 128 + n0;
#pragma unroll
                    for (int g = 0; g < 4; ++g) {
                        int n = nc * 128 + n0 + g * 4;
                        float4 v = (n < NH) ? *(const float4*)(src + g * 4)
                                            : make_float4(0.f, 0.f, 0.f, 0.f);
                        *(float4*)&T[kl][n0 + g * 4] = v;
                    }
                }
                __syncthreads();
#pragma unroll
                for (int s = 0; s < 2; ++s) {
                    int idx = s * 256 + t;     // 0..511
                    int row = idx >> 2, cl = idx & 3, c = h * 4 + cl;
                    bf16x8 v = pack8(T[cl * 8 + 0][row], T[cl * 8 + 1][row],
                                     T[cl * 8 + 2][row], T[cl * 8 + 3][row],
                                     T[cl * 8 + 4][row], T[cl * 8 + 5][row],
                                     T[cl * 8 + 6][row], T[cl * 8 + 7][row]);
                    *(bf16x8*)&img[row * 64 + ((c ^ (row & 7)) << 3)] = v;
                }
                __syncthreads();
            }
        } else if (bid < 672) {
            int e = bid - 160;
            int it = e & 63, nc = (e >> 6) & 1, zz = e >> 7;
            float (*Tp)[84] = reinterpret_cast<float(*)[84]>(&T[0][0]);
            {
                int kidx = t >> 3, part = t & 7;   // 10 n per thread
                int korig = (kidx < 16) ? (2048 + it * 16 + kidx)
                                        : (3072 + it * 16 + (kidx - 16));
                const float* src = W0 + (size_t)korig * NH;
#pragma unroll
                for (int g = 0; g < 10; ++g) {
                    int n = nc * 320 + zz * 80 + part * 10 + g;
                    Tp[kidx][part * 10 + g] = (n < NH) ? src[n] : 0.0f;
                }
            }
            __syncthreads();
            __bf16* img = W0pair + ((size_t)nc * 64 + it) * IMGQ;
#pragma unroll
            for (int s = 0; s < 2; ++s) {
                int idx = s * 256 + t;   // (rloc, c)
                if (idx < 320) {
                    int rloc = idx >> 2, c = idx & 3;
                    bf16x8 v = pack8(Tp[c * 8 + 0][rloc], Tp[c * 8 + 1][rloc],
                                     Tp[c * 8 + 2][rloc], Tp[c * 8 + 3][rloc],
                                     Tp[c * 8 + 4][rloc], Tp[c * 8 + 5][rloc],
                                     Tp[c * 8 + 6][rloc], Tp[c * 8 + 7][rloc]);
                    int rg = zz * 80 + rloc;
                    int slot = ((rg >> 1) + c) & 3;
                    *(bf16x8*)&img[rg * 32 + slot * 8] = v;
                }
            }
        } else {
            int j = ((bid - 672) * 256 + t) * 8;
            float4 z = make_float4(0.f, 0.f, 0.f, 0.f);
            if (j + 8 <= out_size) {
                *(float4*)(out + j) = z;
                *(float4*)(out + j + 4) = z;
            }
        }
    }
}

// ---------------------------------------------------------------------------
// Kernel 2: pre-projection GEMMs. Full-K single pass, plain direct stores,
// 3-buffer counted-vmcnt pipeline (R5 config, FROZEN).
// 64x64 tiles, block = 256 (4 waves, 2x2 of 32x32).
// grid = (24 mtile [0..7 trig, 8..23 ent], 10 ntile of 64).
__global__ __launch_bounds__(256) void pre_mfma_kernel(
    const float* __restrict__ trig, const float* __restrict__ ent,
    const __bf16* __restrict__ W0pre, float* __restrict__ pre_t,
    float* __restrict__ pre_e) {
    __shared__ __bf16 As[2][64 * 64];
    __shared__ __bf16 Bs[3][64 * 64];
    int mt8 = blockIdx.x, ntile = blockIdx.y;
    const float* A;
    float* C;
    int kbofs, mbase;
    if (mt8 < 8) { A = trig; C = pre_t; kbofs = 0;  mbase = mt8 * 64; }
    else         { A = ent;  C = pre_e; kbofs = 16; mbase = (mt8 - 8) * 64; }
    int tid = threadIdx.x;
    int lane = tid & 63, w = tid >> 6, rw = w & 1, cw = w >> 1;
    int q = lane >> 4, l15 = lane & 15, sa = l15 & 7;
    int nc = ntile >> 1, half = ntile & 1;
    const __bf16* imgbase =
        W0pre + ((size_t)nc * 32 + kbofs) * IMGP + half * 4096;
    int ar = tid >> 2, seg = tid & 3;
    f32x4 acc[2][2] = {};
    float4 av[4];

    auto dma_bb = [&](int it, int buf) {
        const __bf16* img = imgbase + (size_t)it * IMGP;
#pragma unroll
        for (int i = 0; i < 2; ++i) {
            int idx = i * 4 + w;
            dma16(img + idx * 512 + lane * 8, (__bf16*)Bs[buf] + idx * 512);
        }
    };
    auto load_a = [&](int it) {
        const float* src = A + (size_t)(mbase + ar) * ND + it * 64;
#pragma unroll
        for (int i = 0; i < 2; ++i) {
            int c = seg * 2 + i;
            av[i * 2]     = *(const float4*)(src + c * 8);
            av[i * 2 + 1] = *(const float4*)(src + c * 8 + 4);
        }
    };
    auto write_a = [&](int buf) {
#pragma unroll
        for (int i = 0; i < 2; ++i) {
            int c = seg * 2 + i;
            float4 a0 = av[i * 2], a1 = av[i * 2 + 1];
            *(bf16x8*)&As[buf][ar * 64 + ((c ^ (ar & 7)) << 3)] =
                pack8(a0.x, a0.y, a0.z, a0.w, a1.x, a1.y, a1.z, a1.w);
        }
    };
    auto mfma_t = [&](int abuf, int bbuf) {
#pragma unroll
        for (int ks = 0; ks < 2; ++ks) {
            int coff = ((q ^ sa) ^ (ks << 2)) << 3;
            bf16x8 af[2];
#pragma unroll
            for (int mt = 0; mt < 2; ++mt)
                af[mt] = *(const bf16x8*)&As[abuf][(32 * rw + 16 * mt + l15) * 64 + coff];
#pragma unroll
            for (int nt = 0; nt < 2; ++nt) {
                bf16x8 bf = *(const bf16x8*)&Bs[bbuf][(32 * cw + 16 * nt + l15) * 64 + coff];
#pragma unroll
                for (int mt = 0; mt < 2; ++mt)
                    acc[mt][nt] = __builtin_amdgcn_mfma_f32_16x16x32_bf16(
                        af[mt], bf, acc[mt][nt], 0, 0, 0);
            }
        }
    };

    // preamble: A(0) loads oldest, then DMA(0), DMA(1); full drain once.
    load_a(0);
    dma_bb(0, 0);
    dma_bb(1, 1);
    write_a(0);
    __syncthreads();

    int bc = 0, bp = 2;
    for (int it = 0; it < 16; ++it) {
        int acur = it & 1, anxt = acur ^ 1;
        if (it < 15) load_a(it + 1);       // oldest new loads
        if (it < 14) dma_bb(it + 2, bp);   // 2-ahead, stays in flight
        __builtin_amdgcn_s_setprio(1);
        mfma_t(acur, bc);
        __builtin_amdgcn_s_setprio(0);
        if (it < 15) write_a(anxt);        // vm-wait drains dma(it+1)
        LGKM_BARRIER();
        bc = (bc == 2) ? 0 : bc + 1;
        bp = (bp == 2) ? 0 : bp + 1;
    }

#pragma unroll
    for (int mt = 0; mt < 2; ++mt)
#pragma unroll
        for (int r = 0; r < 4; ++r) {
            float* crow =
                C + (size_t)(mbase + 32 * rw + 16 * mt + 4 * q + r) * NH;
#pragma unroll
            for (int nt = 0; nt < 2; ++nt) {
                int n = ntile * 64 + 32 * cw + 16 * nt + l15;
                if (n < NH) crow[n] = acc[mt][nt][r];
            }
        }
}

// ---------------------------------------------------------------------------
// Kernel 3: pairwise GEMM + fused FFN epilogue. EXACT R4 config (measured
// 100.4 us) + ANTI-PHASE STAGGER (this round's single change): odd-parity
// blocks burn ~1800 cyc once at entry so the two co-resident blocks on a CU
// run in anti-phase - while one block's waves issue MFMA, the other's do
// write_x/loads (m114 co-schedule). One-time cost ~0.75 us.
// 2-buffer, single full-drain barrier/iter; write_x BEFORE mfma_tile;
// e-prefetch 2 iters ahead in named slots; f32 Ts; setprio around MFMA.
// LDS 64 KB; grid = (16 b, 16 tp, 2 nc), block 256.
__global__ __launch_bounds__(256, 2) void pair_mfma_kernel(
    const float* __restrict__ trig, const float* __restrict__ ent,
    const __bf16* __restrict__ W0pair, const float* __restrict__ b0,
    const float* __restrict__ pre_t, const float* __restrict__ pre_e,
    const float* __restrict__ W1, const float* __restrict__ b1,
    float* __restrict__ out) {
    __shared__ __bf16 Xs[2][128 * 32];   // 2 x 8 KB
    __shared__ __bf16 Bs[2][320 * 32];   // 2 x 20 KB
    __shared__ float Ts[2048];           // 8 KB: [trigger 2][k 1024] f32
    int b = blockIdx.x, tp = blockIdx.y, nc = blockIdx.z;
    int tid = threadIdx.x;
    int lane = tid & 63, w = tid >> 6, rw = w & 1, cw = w >> 1;
    int q = lane >> 4, l15 = lane & 15;
    int xr = tid >> 1, xh = tid & 1;     // X staging: row 0..127, k-half
    const float* t0row = trig + (size_t)(b * NT + tp * 2) * ND;
    const float* erow = ent + (size_t)(b * NE + (xr & 63)) * ND;
    const __bf16* imgbase = W0pair + (size_t)nc * 64 * IMGQ;
    f32x4 acc[4][10] = {};
    float4 efA0, efA1, efB0, efB1;       // two named e-prefetch slots

    // Anti-phase stagger: odd blocks delay ~1800 cyc (half an iteration).
    if ((b + tp + nc) & 1) {
#pragma unroll 1
        for (int i = 0; i < 4; ++i) __builtin_amdgcn_s_sleep(7);
    }

    auto dma_b = [&](int it, int buf) {
        const __bf16* img = imgbase + (size_t)it * IMGQ + w * 2560;
        __bf16* lds = &Bs[buf][w * 2560];
#pragma unroll
        for (int i = 0; i < 5; ++i)
            dma16(img + i * 512 + lane * 8, lds + i * 512);
    };
    auto load_eA = [&](int it) {
        const float* er = erow + it * 16 + xh * 8;
        efA0 = *(const float4*)er;
        efA1 = *(const float4*)(er + 4);
    };
    auto load_eB = [&](int it) {
        const float* er = erow + it * 16 + xh * 8;
        efB0 = *(const float4*)er;
        efB1 = *(const float4*)(er + 4);
    };
    auto write_x = [&](int it, int buf, float4 e0, float4 e1) {
        const float* tsp = &Ts[(xr >> 6) * 1024 + it * 16 + xh * 8];
        float4 t0 = *(const float4*)tsp;
        float4 t1 = *(const float4*)(tsp + 4);
        float tf[8], ef[8];
        tf[0] = t0.x; tf[1] = t0.y; tf[2] = t0.z; tf[3] = t0.w;
        tf[4] = t1.x; tf[5] = t1.y; tf[6] = t1.z; tf[7] = t1.w;
        ef[0] = e0.x; ef[1] = e0.y; ef[2] = e0.z; ef[3] = e0.w;
        ef[4] = e1.x; ef[5] = e1.y; ef[6] = e1.z; ef[7] = e1.w;
        int sp = (((xr >> 1) + xh) & 3) * 8;
        int sd = (((xr >> 1) + 2 + xh) & 3) * 8;
        __bf16* xb = &Xs[buf][xr * 32];
        *(bf16x8*)(xb + sp) = pack8(
            tf[0] * ef[0], tf[1] * ef[1], tf[2] * ef[2], tf[3] * ef[3],
            tf[4] * ef[4], tf[5] * ef[5], tf[6] * ef[6], tf[7] * ef[7]);
        *(bf16x8*)(xb + sd) = pack8(
            fabsf(tf[0] - ef[0]), fabsf(tf[1] - ef[1]),
            fabsf(tf[2] - ef[2]), fabsf(tf[3] - ef[3]),
            fabsf(tf[4] - ef[4]), fabsf(tf[5] - ef[5]),
            fabsf(tf[6] - ef[6]), fabsf(tf[7] - ef[7]));
    };
    auto mfma_tile = [&](int buf) {
        const __bf16* X = Xs[buf];
        const __bf16* Bb = Bs[buf];
        bf16x8 af[4];
#pragma unroll
        for (int mt = 0; mt < 4; ++mt) {
            int r = 64 * rw + 16 * mt + l15;
            af[mt] = *(const bf16x8*)&X[r * 32 + (((r >> 1) + q) & 3) * 8];
        }
        __builtin_amdgcn_s_setprio(1);
#pragma unroll
        for (int nt = 0; nt < 10; ++nt) {
            int r = 160 * cw + 16 * nt + l15;
            bf16x8 bv = *(const bf16x8*)&Bb[r * 32 + (((r >> 1) + q) & 3) * 8];
#pragma unroll
            for (int mt = 0; mt < 4; ++mt)
                acc[mt][nt] = __builtin_amdgcn_mfma_f32_16x16x32_bf16(
                    af[mt], bv, acc[mt][nt], 0, 0, 0);
        }
        __builtin_amdgcn_s_setprio(0);
    };

    // --- preamble: trigger rows -> Ts (f32, straight copy) ---
    {
        int k0 = (tid & 127) * 8;
        int row = tid >> 7;
        const float* src = t0row + row * ND + k0;
        float4 va = *(const float4*)src;
        float4 vb = *(const float4*)(src + 4);
        *(float4*)&Ts[row * 1024 + k0] = va;
        *(float4*)&Ts[row * 1024 + k0 + 4] = vb;
    }
    load_eA(0);                  // write_x(0) consumes slot A
    dma_b(0, 0);
    __syncthreads();             // Ts + B(0) + e(0) ready (full drain)
    load_eB(1);                  // issue early; overlaps write_x(0) VALU
    write_x(0, 0, efA0, efA1);
    __syncthreads();             // X(0) visible

    // Main loop, 2 iters per body for static ef-slot + buffer indices.
    // write_x(it) consumes slot (it&1): A=even, B=odd.
    for (int itp = 0; itp < 32; ++itp) {
        int it0 = itp * 2;       // even: cur=0, nxt=1
        int it1 = it0 + 1;       // odd:  cur=1, nxt=0
        // --- even iteration ---
        if (it0 < 62) load_eA(it0 + 2);          // fills slot A (even)
        dma_b(it0 + 1, 1);
        write_x(it0 + 1, 1, efB0, efB1);         // slot B (odd), loaded 1 iter ago
        mfma_tile(0);
        __syncthreads();         // drains dma(it0+1) + e-loads, publishes X
        // --- odd iteration ---
        if (it1 < 62) load_eB(it1 + 2);          // fills slot B (odd)
        if (it1 < 63) {
            dma_b(it1 + 1, 0);
            write_x(it1 + 1, 0, efA0, efA1);     // slot A (even)
        }
        mfma_tile(1);
        __syncthreads();
    }

    // --- epilogue: h = relu(acc + pre_t + pre_e + b0); out += h @ W1 ---
    int tglob = b * NT + tp * 2 + rw;
    const float* preT = pre_t + (size_t)tglob * NH;
    float w10[10], w11[10], b0v[10], ptv[10];
    int nbase = nc * 320 + 160 * cw + l15;
#pragma unroll
    for (int nt = 0; nt < 10; ++nt) {
        int n = nbase + 16 * nt;
        bool v = n < NH;
        w10[nt] = v ? W1[2 * n] : 0.f;
        w11[nt] = v ? W1[2 * n + 1] : 0.f;
        b0v[nt] = v ? b0[n] : 0.f;
        ptv[nt] = v ? preT[n] : 0.f;
    }
    float b10 = b1[0], b11 = b1[1];
    bool lead = (l15 == 0);
    bool addb = (nc == 0) && (cw == 0);
#pragma unroll
    for (int mt = 0; mt < 4; ++mt) {
#pragma unroll
        for (int r = 0; r < 4; ++r) {
            int e = 16 * mt + 4 * q + r;
            const float* preE = pre_e + (size_t)(b * NE + e) * NH;
            float s0 = 0.f, s1 = 0.f;
#pragma unroll
            for (int nt = 0; nt < 10; ++nt) {
                int n = nbase + 16 * nt;
                float pe = (n < NH) ? preE[n] : 0.f;
                float h = acc[mt][nt][r] + ptv[nt] + pe + b0v[nt];
                h = fmaxf(h, 0.f);
                s0 += h * w10[nt];
                s1 += h * w11[nt];
            }
#pragma unroll
            for (int m = 8; m >= 1; m >>= 1) {
                s0 += __shfl_xor(s0, m);
                s1 += __shfl_xor(s1, m);
            }
            if (lead) {
                if (addb) { s0 += b10; s1 += b11; }
                float* o = out + ((size_t)(tglob * NE + e)) * 2;
                atomicAdd(o, s0);
                atomicAdd(o + 1, s1);
            }
        }
    }
}

// ---------------------------------------------------------------------------
extern "C" void kernel_launch(void* const* d_in, const int* in_sizes, int n_in,
                              void* d_out, int out_size, void* d_ws,
                              size_t ws_size, hipStream_t stream) {
    const float* piece = (const float*)d_in[0];
    const int* widx = (const int*)d_in[1];
    const int* tidx = (const int*)d_in[2];
    const int* eidx = (const int*)d_in[3];
    const float* W0 = (const float*)d_in[4];
    const float* b0 = (const float*)d_in[5];
    const float* W1 = (const float*)d_in[6];
    const float* b1 = (const float*)d_in[7];
    float* out = (float*)d_out;

    float* ws = (float*)d_ws;
    float* trig = ws;                               // NB*NT*ND f32
    float* ent = trig + (size_t)NB * NT * ND;       // NB*NE*ND f32
    float* pre_t = ent + (size_t)NB * NE * ND;      // NB*NT*NH f32
    float* pre_e = pre_t + (size_t)NB * NT * NH;    // NB*NE*NH f32
    __bf16* W0pre = (__bf16*)(pre_e + (size_t)NB * NE * NH); // 5*32*IMGP bf16
    __bf16* W0pair = W0pre + (size_t)5 * 32 * IMGP;          // 2*64*IMGQ bf16

    // 3 launches: prep (span + builders + zeroing), pre (full-K), pair.
    int nprep = NB * (NT + NE) + 704;  // 1536 + 704
    prep_kernel<<<nprep, 256, 0, stream>>>(piece, widx, tidx, eidx, W0, W0pre,
                                           W0pair, trig, ent, out, out_size);
    pre_mfma_kernel<<<dim3(24, 10), 256, 0, stream>>>(trig, ent, W0pre,
                                                      pre_t, pre_e);
    pair_mfma_kernel<<<dim3(16, 16, 2), 256, 0, stream>>>(
        trig, ent, W0pair, b0, pre_t, pre_e, W1, b1, out);
}